// Round 11
// baseline (56.708 us; speedup 1.0000x reference)
//
#include <hip/hip_runtime.h>

#define KS    7
#define RAD   3
#define TW    32            // tile width (output px)
#define TH    16            // tile height
#define HC    38            // TW + 2*RAD
#define HR    22            // TH + 2*RAD
#define NT    (HR*HC)       // 836 staging sites
#define PAIRS 21            // col-pairs per parity row
#define H     256
#define W     256
#define HWp   (H*W)
#define REPS  3             // DIAGNOSTIC: repeat compute phase (reps 0..REPS-2 discarded)

typedef __fp16    h2raw __attribute__((ext_vector_type(2)));
typedef _Float16  f16x2 __attribute__((ext_vector_type(2)));

__device__ __forceinline__ unsigned pk(float a, float b) {
    h2raw h = __builtin_amdgcn_cvt_pkrtz(a, b);
    return __builtin_bit_cast(unsigned, h);
}
__device__ __forceinline__ f16x2 pkh(float a, float b) {
    return __builtin_bit_cast(f16x2, __builtin_amdgcn_cvt_pkrtz(a, b));
}

#if __has_builtin(__builtin_amdgcn_fdot2)
__device__ __forceinline__ float fdot2(f16x2 a, f16x2 b, float c) {
    return __builtin_amdgcn_fdot2(a, b, c, false);
}
#else
__device__ __forceinline__ float fdot2(f16x2 a, f16x2 b, float c) {
    return c + (float)a.x * (float)b.x + (float)a.y * (float)b.y;
}
#endif

__global__ __launch_bounds__(256, 4)
void bilateral_kernel(const float* __restrict__ in,      // [B][32][H][W]
                      const float* __restrict__ guide,   // [B][3][H][W]
                      const float* __restrict__ sigma_p, // [1]
                      float* __restrict__ out)           // [B][32][H][W]
{
    __shared__ uint4 dt2[HR * 2 * PAIRS];   // input: 8ch fp16 per site
    __shared__ uint2 gt2[HR * 2 * PAIRS];   // guide: {x,y},{z,0} fp16 per site

    const int tid = threadIdx.x;
    const int tx  = tid & 15;
    const int ty  = tid >> 4;
    const int x0  = blockIdx.x * TW;
    const int y0  = blockIdx.y * TH;
    const int b   = blockIdx.z >> 2;
    const int cg0 = (blockIdx.z & 3) * 8;

    const float* gb  = guide + (size_t)b * 3 * HWp;
    const float* inb = in    + ((size_t)b * 32 + cg0) * HWp;

    const float sigma = sigma_p[0];
    const float isig2 = 1.0f / (sigma * sigma);
    const float L2E   = 1.442695041f;
    float lnT2[KS];
#pragma unroll
    for (int i = 0; i < KS; ++i) {
        float r = (float)(i - RAD);
        lnT2[i] = -0.5f * r * r * isig2 * L2E;
    }

    // ---- stage: guide fp16 (uint2) + input 8ch fp16 (uint4), zero halo ----
#pragma unroll
    for (int it = 0; it < 4; ++it) {
        int idx = tid + it * 256;
        if (idx < NT) {
            int row = idx / HC;
            int col = idx - row * HC;
            int gy = y0 - RAD + row, gx = x0 - RAD + col;
            uint2 gv = make_uint2(0u, 0u);
            uint4 pv = make_uint4(0u, 0u, 0u, 0u);
            if (gy >= 0 && gy < H && gx >= 0 && gx < W) {
                int off = gy * W + gx;
                gv.x = pk(gb[off], gb[HWp + off]);
                gv.y = pk(gb[2 * HWp + off], 0.f);
                float v0 = inb[off],           v1 = inb[HWp + off];
                float v2 = inb[2 * HWp + off], v3 = inb[3 * HWp + off];
                float v4 = inb[4 * HWp + off], v5 = inb[5 * HWp + off];
                float v6 = inb[6 * HWp + off], v7 = inb[7 * HWp + off];
                pv.x = pk(v0, v1); pv.y = pk(v2, v3);
                pv.z = pk(v4, v5); pv.w = pk(v6, v7);
            }
            int s = (row * 2 + (col & 1)) * PAIRS + (col >> 1);
            gt2[s] = gv;
            dt2[s] = pv;
        }
    }
    __syncthreads();

    // centers held as opaque-able u32 words
    const int cb = (ty + RAD) * 2 * PAIRS;
    uint2 c0r = gt2[cb + PAIRS + tx + 1];
    uint2 c1r = gt2[cb + tx + 2];
    unsigned u0x = c0r.x, u0z = c0r.y, u1x = c1r.x, u1z = c1r.y;

    float n0, n1;
    float a0[8], a1[8];

#pragma unroll 1
    for (int rep = 0; rep < REPS; ++rep) {
        // opaque-modify centers: forces full recompute each rep (rule #17)
        asm volatile("" : "+v"(u0x), "+v"(u0z), "+v"(u1x), "+v"(u1z));
        const f16x2 nc0xy = -__builtin_bit_cast(f16x2, u0x);
        const f16x2 nc0z  = -__builtin_bit_cast(f16x2, u0z);
        const f16x2 nc1xy = -__builtin_bit_cast(f16x2, u1x);
        const f16x2 nc1z  = -__builtin_bit_cast(f16x2, u1z);

        n0 = 0.f; n1 = 0.f;
#pragma unroll
        for (int c = 0; c < 8; ++c) { a0[c] = 0.f; a1[c] = 0.f; }

#pragma unroll
        for (int i = 0; i < KS; ++i) {
            const int rb = (ty + i) * 2 * PAIRS;
            uint2 gq[8];
            uint4 rq[8];
#pragma unroll
            for (int k = 0; k < 8; ++k) {
                int s = rb + (k & 1) * PAIRS + tx + (k >> 1);
                gq[k] = gt2[s];
                rq[k] = dt2[s];
            }
            f16x2 A0[4], A1[4];
#pragma unroll
            for (int k = 0; k < 4; ++k) { A0[k] = (f16x2)0; A1[k] = (f16x2)0; }
#pragma unroll
            for (int dj = 0; dj < KS; ++dj) {
                const float lnE = lnT2[i] + lnT2[dj];
                f16x2 gxy = __builtin_bit_cast(f16x2, gq[dj].x);
                f16x2 gz  = __builtin_bit_cast(f16x2, gq[dj].y);
                f16x2 dxy = gxy + nc0xy;
                f16x2 dz  = gz + nc0z;
                float s0 = fdot2(dxy, dxy, fdot2(dz, dz, 0.f));
                float w0 = exp2f(fmaf(s0, -0.5f * L2E, lnE));
                n0 += w0;
                f16x2 w0h = pkh(w0, w0);
                A0[0] = w0h * __builtin_bit_cast(f16x2, rq[dj].x) + A0[0];
                A0[1] = w0h * __builtin_bit_cast(f16x2, rq[dj].y) + A0[1];
                A0[2] = w0h * __builtin_bit_cast(f16x2, rq[dj].z) + A0[2];
                A0[3] = w0h * __builtin_bit_cast(f16x2, rq[dj].w) + A0[3];
                gxy = __builtin_bit_cast(f16x2, gq[dj + 1].x);
                gz  = __builtin_bit_cast(f16x2, gq[dj + 1].y);
                dxy = gxy + nc1xy;
                dz  = gz + nc1z;
                float s1 = fdot2(dxy, dxy, fdot2(dz, dz, 0.f));
                float w1 = exp2f(fmaf(s1, -0.5f * L2E, lnE));
                n1 += w1;
                f16x2 w1h = pkh(w1, w1);
                A1[0] = w1h * __builtin_bit_cast(f16x2, rq[dj + 1].x) + A1[0];
                A1[1] = w1h * __builtin_bit_cast(f16x2, rq[dj + 1].y) + A1[1];
                A1[2] = w1h * __builtin_bit_cast(f16x2, rq[dj + 1].z) + A1[2];
                A1[3] = w1h * __builtin_bit_cast(f16x2, rq[dj + 1].w) + A1[3];
            }
#pragma unroll
            for (int k = 0; k < 4; ++k) {
                a0[2 * k]     += (float)A0[k].x;
                a0[2 * k + 1] += (float)A0[k].y;
                a1[2 * k]     += (float)A1[k].x;
                a1[2 * k + 1] += (float)A1[k].y;
            }
        }

        if (rep < REPS - 1) {
            // consume results opaquely (keep reps live), then recompute
            asm volatile("" :: "v"(n0), "v"(n1));
#pragma unroll
            for (int c = 0; c < 8; ++c)
                asm volatile("" :: "v"(a0[c]), "v"(a1[c]));
        }
    }

    // ---- normalize + store ----
    const float i0 = 1.f / n0, i1 = 1.f / n1;
    const int X = x0 + 2 * tx, Y = y0 + ty;
    float* ob = out + ((size_t)b * 32 + cg0) * HWp + (size_t)Y * W + X;
#pragma unroll
    for (int c = 0; c < 8; ++c) {
        float2 s;
        s.x = a0[c] * i0;
        s.y = a1[c] * i1;
        *(float2*)(ob + (size_t)c * HWp) = s;
    }
}

extern "C" void kernel_launch(void* const* d_in, const int* in_sizes, int n_in,
                              void* d_out, int out_size, void* d_ws, size_t ws_size,
                              hipStream_t stream) {
    const float* in    = (const float*)d_in[0];
    const float* guide = (const float*)d_in[1];
    const float* sigma = (const float*)d_in[2];
    float* out = (float*)d_out;
    dim3 grid(W / TW, H / TH, 2 * 4);
    bilateral_kernel<<<grid, dim3(256), 0, stream>>>(in, guide, sigma, out);
}

// Round 12
// 30.647 us; speedup vs baseline: 1.8504x; 1.8504x over previous
//
#include <hip/hip_runtime.h>

#define KS    7
#define RAD   3
#define TW    32            // tile width (output px)
#define TH    16            // tile height
#define HC    38            // TW + 2*RAD
#define HR    22            // TH + 2*RAD
#define NT    (HR*HC)       // 836 staging sites
#define PAIRS 21            // col-pairs per parity row
#define H     256
#define W     256
#define HWp   (H*W)

typedef __fp16    h2raw __attribute__((ext_vector_type(2)));
typedef _Float16  f16x2 __attribute__((ext_vector_type(2)));

__device__ __forceinline__ unsigned pk(float a, float b) {
    h2raw h = __builtin_amdgcn_cvt_pkrtz(a, b);
    return __builtin_bit_cast(unsigned, h);
}
__device__ __forceinline__ f16x2 pkh(float a, float b) {
    return __builtin_bit_cast(f16x2, __builtin_amdgcn_cvt_pkrtz(a, b));
}

__global__ __launch_bounds__(256, 3)
void bilateral_kernel(const float* __restrict__ in,      // [B][32][H][W]
                      const float* __restrict__ guide,   // [B][3][H][W]
                      const float* __restrict__ sigma_p, // [1]
                      float* __restrict__ out)           // [B][32][H][W]
{
    // parity-split layout: site (row,col) -> [(row*2 + (col&1))*PAIRS + (col>>1)]
    // thread tx reads pairs tx..tx+3 per parity: contiguous, conflict-free,
    // compile-time immediate offsets.
    __shared__ float4 gt2[HR * 2 * PAIRS];  // guide: {x~,y~,z~, q~=-|g~|^2/2} f32
    __shared__ uint4  dt2[HR * 2 * PAIRS];  // input: 8ch fp16 per site

    const int tid = threadIdx.x;
    const int tx  = tid & 15;
    const int ty  = tid >> 4;
    const int x0  = blockIdx.x * TW;
    const int y0  = blockIdx.y * TH;
    const int b   = blockIdx.z >> 2;
    const int cg0 = (blockIdx.z & 3) * 8;

    const float* gb  = guide + (size_t)b * 3 * HWp;
    const float* inb = in    + ((size_t)b * 32 + cg0) * HWp;

    const float sigma = sigma_p[0];
    const float isig2 = 1.0f / (sigma * sigma);
    const float L2E   = 1.442695041f;          // log2(e)
    const float SQL   = 1.201122409f;          // sqrt(log2(e))
    float lnT2[KS];                             // log2-domain spatial factor
#pragma unroll
    for (int i = 0; i < KS; ++i) {
        float r = (float)(i - RAD);
        lnT2[i] = -0.5f * r * r * isig2 * L2E;
    }

    // ---- stage: guide f32 (pre-scaled, with q~) + input 8ch fp16 ----
#pragma unroll
    for (int it = 0; it < 4; ++it) {
        int idx = tid + it * 256;
        if (idx < NT) {
            int row = idx / HC;
            int col = idx - row * HC;
            int gy = y0 - RAD + row, gx = x0 - RAD + col;
            float4 gv = make_float4(0.f, 0.f, 0.f, 0.f);
            uint4  pv = make_uint4(0u, 0u, 0u, 0u);
            if (gy >= 0 && gy < H && gx >= 0 && gx < W) {
                int off = gy * W + gx;
                float gxv = gb[off] * SQL;
                float gyv = gb[HWp + off] * SQL;
                float gzv = gb[2 * HWp + off] * SQL;
                gv.x = gxv; gv.y = gyv; gv.z = gzv;
                gv.w = -0.5f * (gxv * gxv + gyv * gyv + gzv * gzv);
                float v0 = inb[off],           v1 = inb[HWp + off];
                float v2 = inb[2 * HWp + off], v3 = inb[3 * HWp + off];
                float v4 = inb[4 * HWp + off], v5 = inb[5 * HWp + off];
                float v6 = inb[6 * HWp + off], v7 = inb[7 * HWp + off];
                pv.x = pk(v0, v1); pv.y = pk(v2, v3);
                pv.z = pk(v4, v5); pv.w = pk(v6, v7);
            }
            int s = (row * 2 + (col & 1)) * PAIRS + (col >> 1);
            gt2[s] = gv;
            dt2[s] = pv;
        }
    }
    __syncthreads();

    // ---- centers: px0 col 2tx+3 (parity1, pair tx+1); px1 col 2tx+4 (parity0, pair tx+2)
    const int cb = (ty + RAD) * 2 * PAIRS;
    const float4 c0 = gt2[cb + PAIRS + tx + 1];
    const float4 c1 = gt2[cb + tx + 2];
    // Qc = q~_c = -|g~_c|^2/2 is c.w

    float n0 = 0.f, n1 = 0.f;
    float a0[8], a1[8];
#pragma unroll
    for (int c = 0; c < 8; ++c) { a0[c] = 0.f; a1[c] = 0.f; }

    // ---- fused weight+apply; f32 weight math, fp16 row-accumulate ----
#pragma unroll
    for (int i = 0; i < KS; ++i) {
        const int rb = (ty + i) * 2 * PAIRS;
        float4 gq[8];
        uint4  rq[8];
#pragma unroll
        for (int k = 0; k < 8; ++k) {
            int s = rb + (k & 1) * PAIRS + tx + (k >> 1);  // col 2tx+k
            gq[k] = gt2[s];
            rq[k] = dt2[s];
        }
        const float Qci0 = c0.w + lnT2[i];
        const float Qci1 = c1.w + lnT2[i];
        f16x2 A0[4], A1[4];
#pragma unroll
        for (int k = 0; k < 4; ++k) { A0[k] = (f16x2)0; A1[k] = (f16x2)0; }
#pragma unroll
        for (int dj = 0; dj < KS; ++dj) {
            // pixel 0: window col 2tx+dj
            float e0 = gq[dj].w + (Qci0 + lnT2[dj]);
            e0 = fmaf(gq[dj].x, c0.x, fmaf(gq[dj].y, c0.y, fmaf(gq[dj].z, c0.z, e0)));
            float w0 = exp2f(e0);
            n0 += w0;
            f16x2 w0h = pkh(w0, w0);
            A0[0] = w0h * __builtin_bit_cast(f16x2, rq[dj].x) + A0[0];
            A0[1] = w0h * __builtin_bit_cast(f16x2, rq[dj].y) + A0[1];
            A0[2] = w0h * __builtin_bit_cast(f16x2, rq[dj].z) + A0[2];
            A0[3] = w0h * __builtin_bit_cast(f16x2, rq[dj].w) + A0[3];
            // pixel 1: window col 2tx+dj+1
            float e1 = gq[dj + 1].w + (Qci1 + lnT2[dj]);
            e1 = fmaf(gq[dj + 1].x, c1.x, fmaf(gq[dj + 1].y, c1.y, fmaf(gq[dj + 1].z, c1.z, e1)));
            float w1 = exp2f(e1);
            n1 += w1;
            f16x2 w1h = pkh(w1, w1);
            A1[0] = w1h * __builtin_bit_cast(f16x2, rq[dj + 1].x) + A1[0];
            A1[1] = w1h * __builtin_bit_cast(f16x2, rq[dj + 1].y) + A1[1];
            A1[2] = w1h * __builtin_bit_cast(f16x2, rq[dj + 1].z) + A1[2];
            A1[3] = w1h * __builtin_bit_cast(f16x2, rq[dj + 1].w) + A1[3];
        }
        // flush row accumulators to f32 (bounds fp16 chain at 7 adds)
#pragma unroll
        for (int k = 0; k < 4; ++k) {
            a0[2 * k]     += (float)A0[k].x;
            a0[2 * k + 1] += (float)A0[k].y;
            a1[2 * k]     += (float)A1[k].x;
            a1[2 * k + 1] += (float)A1[k].y;
        }
    }

    // ---- normalize + store (norm >= center weight ~= 1, never 0) ----
    const float i0 = 1.f / n0, i1 = 1.f / n1;
    const int X = x0 + 2 * tx, Y = y0 + ty;
    float* ob = out + ((size_t)b * 32 + cg0) * HWp + (size_t)Y * W + X;
#pragma unroll
    for (int c = 0; c < 8; ++c) {
        float2 s;
        s.x = a0[c] * i0;
        s.y = a1[c] * i1;
        *(float2*)(ob + (size_t)c * HWp) = s;
    }
}

extern "C" void kernel_launch(void* const* d_in, const int* in_sizes, int n_in,
                              void* d_out, int out_size, void* d_ws, size_t ws_size,
                              hipStream_t stream) {
    const float* in    = (const float*)d_in[0];
    const float* guide = (const float*)d_in[1];
    const float* sigma = (const float*)d_in[2];
    float* out = (float*)d_out;
    dim3 grid(W / TW, H / TH, 2 * 4);
    bilateral_kernel<<<grid, dim3(256), 0, stream>>>(in, guide, sigma, out);
}

// Round 13
// 25.030 us; speedup vs baseline: 2.2656x; 1.2244x over previous
//
#include <hip/hip_runtime.h>

#define KS    7
#define RAD   3
#define TW    32            // tile width (output px)
#define TH    16            // tile height
#define HC    38            // halo cols
#define HR    22            // halo rows
#define PAIRS 21            // col-pairs per parity row (19 needed, +2 pad)
#define NSITE (HR*2*PAIRS)  // 924 physical sites
#define H     256
#define W     256
#define HWp   (H*W)

typedef __fp16    h2raw __attribute__((ext_vector_type(2)));
typedef _Float16  f16x2 __attribute__((ext_vector_type(2)));

__device__ __forceinline__ unsigned pk(float a, float b) {
    h2raw h = __builtin_amdgcn_cvt_pkrtz(a, b);
    return __builtin_bit_cast(unsigned, h);
}
__device__ __forceinline__ f16x2 pkh(float a, float b) {
    return __builtin_bit_cast(f16x2, __builtin_amdgcn_cvt_pkrtz(a, b));
}

__global__ __launch_bounds__(512, 2)
void bilateral_kernel(const float* __restrict__ in,      // [B][32][H][W]
                      const float* __restrict__ guide,   // [B][3][H][W]
                      const float* __restrict__ sigma_p, // [1]
                      float* __restrict__ out)           // [B][32][H][W]
{
    // parity-split site: (row,col) -> (row*2 + (col&1))*PAIRS + (col>>1)
    __shared__ float4 gt2[NSITE];                 // guide {x~,y~,z~,q~}, f32
    __shared__ __align__(16) unsigned dtu[4][NSITE * 4];  // 4 groups x 8ch fp16/site

    const int tid = threadIdx.x;
    const int tx  = tid & 31;            // 0..31 (output col in tile)
    const int ty  = tid >> 5;            // 0..15 (output row in tile)
    const int x0  = blockIdx.x * TW;
    const int y0  = blockIdx.y * TH;
    const int b   = blockIdx.z;

    const float* gb  = guide + (size_t)b * 3  * HWp;
    const float* inb = in    + (size_t)b * 32 * HWp;

    const float sigma = sigma_p[0];
    const float isig2 = 1.0f / (sigma * sigma);
    const float L2E   = 1.442695041f;          // log2(e)
    const float SQL   = 1.201122409f;          // sqrt(log2(e))
    float lnT2[KS];
#pragma unroll
    for (int i = 0; i < KS; ++i) {
        float r = (float)(i - RAD);
        lnT2[i] = -0.5f * r * r * isig2 * L2E;
    }

    // ---- guide staging: 220 quad-tasks (row, q). quads all-in or all-out. ----
    for (int t = tid; t < HR * 10; t += 512) {
        int row = t / 10, q = t - row * 10;
        int gy  = y0 - RAD + row;
        int gxb = x0 - 4 + 4 * q;                 // 4-aligned
        bool v = (gy >= 0) && (gy < H) && (gxb >= 0) && (gxb < W);
        float4 X = make_float4(0.f, 0.f, 0.f, 0.f);
        float4 Y = X, Z = X;
        if (v) {
            const float* p = gb + gy * W + gxb;
            X = *(const float4*)p;
            Y = *(const float4*)(p + HWp);
            Z = *(const float4*)(p + 2 * HWp);
        }
        int s0 = row * 2 * PAIRS + 2 * q;         // site of col 4q (parity0)
        // j: col = 4q-1+j -> sites {s0+PAIRS-1, s0, s0+PAIRS, s0+1}
        const float xs[4] = {X.x, X.y, X.z, X.w};
        const float ys[4] = {Y.x, Y.y, Y.z, Y.w};
        const float zs[4] = {Z.x, Z.y, Z.z, Z.w};
        const int   st[4] = {s0 + PAIRS - 1, s0, s0 + PAIRS, s0 + 1};
#pragma unroll
        for (int j = 0; j < 4; ++j) {
            if ((q == 0 && j == 0) || (q == 9 && j == 3)) continue;  // col -1 / 38
            float ax = xs[j] * SQL, ay = ys[j] * SQL, az = zs[j] * SQL;
            float4 gv;
            gv.x = ax; gv.y = ay; gv.z = az;
            gv.w = -0.5f * (ax * ax + ay * ay + az * az);
            gt2[st[j]] = gv;
        }
    }

    // ---- input staging: 3520 tasks (row, q, cpair) ----
    for (int t = tid; t < HR * 10 * 16; t += 512) {
        int row = t / 160;
        int rem = t - row * 160;
        int q   = rem >> 4;
        int cp  = rem & 15;                       // channel pair 0..15
        int gy  = y0 - RAD + row;
        int gxb = x0 - 4 + 4 * q;
        bool v = (gy >= 0) && (gy < H) && (gxb >= 0) && (gxb < W);
        float4 A = make_float4(0.f, 0.f, 0.f, 0.f), B = A;
        if (v) {
            const float* p = inb + (size_t)(2 * cp) * HWp + gy * W + gxb;
            A = *(const float4*)p;
            B = *(const float4*)(p + HWp);
        }
        int s0 = row * 2 * PAIRS + 2 * q;
        unsigned* dst = &dtu[cp >> 2][cp & 3];
        if (q != 0) dst[(s0 + PAIRS - 1) * 4] = pk(A.x, B.x);
        dst[s0 * 4]           = pk(A.y, B.y);
        dst[(s0 + PAIRS) * 4] = pk(A.z, B.z);
        if (q != 9) dst[(s0 + 1) * 4]     = pk(A.w, B.w);
    }
    __syncthreads();

    // ---- per-column site offsets (runtime tx, hoisted out of all loops) ----
    int colAdd[KS];
#pragma unroll
    for (int k = 0; k < KS; ++k) {
        int col = tx + k;
        colAdd[k] = (col & 1) * PAIRS + (col >> 1);
    }

    // ---- weights: 49 per thread (1 px), f32 log2-domain ----
    const int ccol = tx + RAD;
    const float4 c0 = gt2[(ty + RAD) * 2 * PAIRS + (ccol & 1) * PAIRS + (ccol >> 1)];
    float wk[KS * KS];
    float nsum = 0.f;
#pragma unroll
    for (int i = 0; i < KS; ++i) {
        const int rb = (ty + i) * 2 * PAIRS;
        const float Qci = c0.w + lnT2[i];
#pragma unroll
        for (int k = 0; k < KS; ++k) {
            float4 g = gt2[rb + colAdd[k]];
            float e = g.w + (Qci + lnT2[k]);
            e = fmaf(g.x, c0.x, fmaf(g.y, c0.y, fmaf(g.z, c0.z, e)));
            float w = exp2f(e);
            nsum += w;
            wk[i * KS + k] = w;
        }
    }
    const float inv = 1.f / nsum;   // >= center weight = 1, never 0

    // ---- apply: 4 channel-group phases, fp16 accumulate, f32 flush/row ----
    const int X = x0 + tx, Yo = y0 + ty;
#pragma unroll
    for (int g = 0; g < 4; ++g) {
        const uint4* dg = (const uint4*)&dtu[g][0];
        float acc[8];
#pragma unroll
        for (int c = 0; c < 8; ++c) acc[c] = 0.f;
#pragma unroll
        for (int i = 0; i < KS; ++i) {
            const int rb = (ty + i) * 2 * PAIRS;
            uint4 rq[KS];
#pragma unroll
            for (int k = 0; k < KS; ++k) rq[k] = dg[rb + colAdd[k]];
            f16x2 A0 = (f16x2)0, A1 = (f16x2)0, A2 = (f16x2)0, A3 = (f16x2)0;
#pragma unroll
            for (int k = 0; k < KS; ++k) {
                float w = wk[i * KS + k];
                f16x2 wh = pkh(w, w);
                A0 = wh * __builtin_bit_cast(f16x2, rq[k].x) + A0;
                A1 = wh * __builtin_bit_cast(f16x2, rq[k].y) + A1;
                A2 = wh * __builtin_bit_cast(f16x2, rq[k].z) + A2;
                A3 = wh * __builtin_bit_cast(f16x2, rq[k].w) + A3;
            }
            acc[0] += (float)A0.x; acc[1] += (float)A0.y;
            acc[2] += (float)A1.x; acc[3] += (float)A1.y;
            acc[4] += (float)A2.x; acc[5] += (float)A2.y;
            acc[6] += (float)A3.x; acc[7] += (float)A3.y;
        }
        float* ob = out + ((size_t)b * 32 + 8 * g) * HWp + (size_t)Yo * W + X;
#pragma unroll
        for (int c = 0; c < 8; ++c)
            ob[(size_t)c * HWp] = acc[c] * inv;
    }
}

extern "C" void kernel_launch(void* const* d_in, const int* in_sizes, int n_in,
                              void* d_out, int out_size, void* d_ws, size_t ws_size,
                              hipStream_t stream) {
    const float* in    = (const float*)d_in[0];
    const float* guide = (const float*)d_in[1];
    const float* sigma = (const float*)d_in[2];
    float* out = (float*)d_out;
    dim3 grid(W / TW, H / TH, 2);
    bilateral_kernel<<<grid, dim3(512), 0, stream>>>(in, guide, sigma, out);
}